// Round 1
// baseline (2838.187 us; speedup 1.0000x reference)
//
#include <hip/hip_runtime.h>
#include <math.h>

#define NF 1433
#define NH 16
#define NC 7
#define WPSTRIDE 1436   // 1433 padded to multiple of 4 (16B-aligned rows)

// ---------------- degree ----------------
__global__ void k_deg_init(float* __restrict__ deg, int n) {
  int i = blockIdx.x * blockDim.x + threadIdx.x;
  if (i < n) deg[i] = 1.0f;  // self-loop contributes 1 to every node
}

__global__ void k_deg_count(const int* __restrict__ dst, float* __restrict__ deg, int E) {
  int stride = gridDim.x * blockDim.x;
  for (int e = blockIdx.x * blockDim.x + threadIdx.x; e < E; e += stride)
    atomicAdd(&deg[dst[e]], 1.0f);
}

__global__ void k_rsqrt(float* __restrict__ deg, int n) {
  int i = blockIdx.x * blockDim.x + threadIdx.x;
  if (i < n) deg[i] = rsqrtf(deg[i]);  // deg >= 1 always
}

// ---------------- W1 phase-shifted transpose ----------------
// Wp[s][j][u] = W1[(u+s)][j]  (0 if u+s >= NF), row stride WPSTRIDE
__global__ void k_w1t(const float* __restrict__ W1, float* __restrict__ Wp) {
  int t = blockIdx.x * blockDim.x + threadIdx.x;
  if (t >= 4 * NH * WPSTRIDE) return;
  int u = t % WPSTRIDE;
  int j = (t / WPSTRIDE) % NH;
  int s = t / (WPSTRIDE * NH);
  int k = u + s;
  Wp[t] = (k < NF) ? W1[k * NH + j] : 0.0f;
}

// ---------------- GEMM1: h1 = x @ W1 ; agg1 = h1 * dis^2 (self-loop init) ----
// wave = 16 rows. lane: q = lane>>4 selects row phase, j = lane&15 selects col.
// lane accumulates rows {base+q+4r}, full K per lane -> no cross-lane reduce.
// phase s = (4-q)&3 makes x+row*1433+s 16B-aligned; Wp[s] matches that shift.
__global__ __launch_bounds__(256) void k_gemm1(
    const float* __restrict__ x, const float* __restrict__ W1,
    const float* __restrict__ Wp, const float* __restrict__ dis,
    float* __restrict__ h1, float* __restrict__ agg1, int n) {
  int wave = (blockIdx.x * blockDim.x + threadIdx.x) >> 6;
  int lane = threadIdx.x & 63;
  int nwaves = (n + 15) >> 4;
  if (wave >= nwaves) return;
  int q = lane >> 4, j = lane & 15;
  int base = wave << 4;

  float acc[4] = {0.f, 0.f, 0.f, 0.f};
  int rows[4];
  const float* xr[4];
#pragma unroll
  for (int r = 0; r < 4; ++r) {
    rows[r] = base + q + 4 * r;
    xr[r] = x + (size_t)rows[r] * NF;
  }

  if (base + 15 < n) {  // fast path (n=100000 is divisible by 16 -> always)
    int s = (4 - q) & 3;
    const float4* wv = (const float4*)(Wp + (size_t)(s * NH + j) * WPSTRIDE);
    const float4* xv[4];
#pragma unroll
    for (int r = 0; r < 4; ++r) xv[r] = (const float4*)(xr[r] + s);

    // scalar prologue: k in [0, s)
    for (int k = 0; k < s; ++k) {
      float w = W1[k * NH + j];
#pragma unroll
      for (int r = 0; r < 4; ++r) acc[r] = fmaf(xr[r][k], w, acc[r]);
    }
    // vector body: u = 4m..4m+3, k = u+s, m in [0, 357)
#pragma unroll 4
    for (int m = 0; m < 357; ++m) {
      float4 w = wv[m];
#pragma unroll
      for (int r = 0; r < 4; ++r) {
        float4 xx = xv[r][m];
        acc[r] = fmaf(xx.x, w.x, acc[r]);
        acc[r] = fmaf(xx.y, w.y, acc[r]);
        acc[r] = fmaf(xx.z, w.z, acc[r]);
        acc[r] = fmaf(xx.w, w.w, acc[r]);
      }
    }
    // scalar epilogue: k in [s+1428, 1433)
    for (int k = s + 1428; k < NF; ++k) {
      float w = W1[k * NH + j];
#pragma unroll
      for (int r = 0; r < 4; ++r) acc[r] = fmaf(xr[r][k], w, acc[r]);
    }
  } else {  // tail-safe scalar path
    for (int r = 0; r < 4; ++r) {
      if (rows[r] >= n) continue;
      float a = 0.f;
      for (int k = 0; k < NF; ++k) a = fmaf(xr[r][k], W1[k * NH + j], a);
      acc[r] = a;
    }
  }

#pragma unroll
  for (int r = 0; r < 4; ++r) {
    if (rows[r] < n) {
      float d = dis[rows[r]];
      size_t o = (size_t)rows[r] * NH + j;
      h1[o] = acc[r];
      agg1[o] = acc[r] * d * d;
    }
  }
}

// ---------------- edge scatter, layer 1 (16 feats, 4 threads/edge) ---------
__global__ void k_scatter1(const int* __restrict__ ei, const float* __restrict__ dis,
                           const float* __restrict__ h1, float* __restrict__ agg1, int E) {
  long long total = (long long)E * 4;
  long long stride = (long long)gridDim.x * blockDim.x;
  for (long long t = blockIdx.x * (long long)blockDim.x + threadIdx.x; t < total; t += stride) {
    int e = (int)(t >> 2), p = (int)(t & 3);
    int s = ei[e], d = ei[E + e];
    float c = dis[s] * dis[d];
    float4 hv = *(const float4*)(h1 + (size_t)s * NH + p * 4);
    float* ap = agg1 + (size_t)d * NH + p * 4;
    atomicAdd(ap + 0, hv.x * c);
    atomicAdd(ap + 1, hv.y * c);
    atomicAdd(ap + 2, hv.z * c);
    atomicAdd(ap + 3, hv.w * c);
  }
}

// ---------------- GEMM2: h2 = relu(agg1+b1) @ W2 ; out = h2 * dis^2 --------
__global__ void k_gemm2(const float* __restrict__ agg1, const float* __restrict__ b1,
                        const float* __restrict__ W2, const float* __restrict__ dis,
                        float* __restrict__ h2, float* __restrict__ out, int n) {
  int i = blockIdx.x * blockDim.x + threadIdx.x;
  if (i >= n) return;
  float v[NH];
  const float4* a4 = (const float4*)(agg1 + (size_t)i * NH);
#pragma unroll
  for (int jj = 0; jj < 4; ++jj) {
    float4 t = a4[jj];
    v[jj * 4 + 0] = t.x; v[jj * 4 + 1] = t.y; v[jj * 4 + 2] = t.z; v[jj * 4 + 3] = t.w;
  }
#pragma unroll
  for (int j = 0; j < NH; ++j) v[j] = fmaxf(v[j] + b1[j], 0.f);
  float d = dis[i];
  float d2 = d * d;
#pragma unroll
  for (int c = 0; c < NC; ++c) {
    float s = 0.f;
#pragma unroll
    for (int j = 0; j < NH; ++j) s = fmaf(v[j], W2[j * NC + c], s);
    h2[(size_t)i * NC + c] = s;
    out[(size_t)i * NC + c] = s * d2;  // self-loop init of layer-2 aggregation
  }
}

// ---------------- edge scatter, layer 2 (7 feats, thread/edge) -------------
__global__ void k_scatter2(const int* __restrict__ ei, const float* __restrict__ dis,
                           const float* __restrict__ h2, float* __restrict__ out, int E) {
  int stride = gridDim.x * blockDim.x;
  for (int e = blockIdx.x * blockDim.x + threadIdx.x; e < E; e += stride) {
    int s = ei[e], d = ei[E + e];
    float c = dis[s] * dis[d];
    const float* hp = h2 + (size_t)s * NC;
    float* op = out + (size_t)d * NC;
#pragma unroll
    for (int k = 0; k < NC; ++k) atomicAdd(op + k, hp[k] * c);
  }
}

// ---------------- relu + bias + log_softmax, in place on out ---------------
__global__ void k_final(const float* __restrict__ b2, float* __restrict__ out, int n) {
  int i = blockIdx.x * blockDim.x + threadIdx.x;
  if (i >= n) return;
  float v[NC];
#pragma unroll
  for (int c = 0; c < NC; ++c) v[c] = fmaxf(out[(size_t)i * NC + c] + b2[c], 0.f);
  float m = v[0];
#pragma unroll
  for (int c = 1; c < NC; ++c) m = fmaxf(m, v[c]);
  float sum = 0.f;
#pragma unroll
  for (int c = 0; c < NC; ++c) sum += expf(v[c] - m);
  float l = logf(sum);
#pragma unroll
  for (int c = 0; c < NC; ++c) out[(size_t)i * NC + c] = v[c] - m - l;
}

extern "C" void kernel_launch(void* const* d_in, const int* in_sizes, int n_in,
                              void* d_out, int out_size, void* d_ws, size_t ws_size,
                              hipStream_t stream) {
  const float* x  = (const float*)d_in[0];
  const int*   ei = (const int*)d_in[1];
  const float* W1 = (const float*)d_in[2];
  const float* b1 = (const float*)d_in[3];
  const float* W2 = (const float*)d_in[4];
  const float* b2 = (const float*)d_in[5];
  int n = in_sizes[0] / NF;   // 100000
  int E = in_sizes[1] / 2;    // 3200000

  float* ws   = (float*)d_ws;
  float* dis  = ws;                                  // n
  float* Wp   = dis + n;                             // 4*16*WPSTRIDE
  float* h1   = Wp + 4 * NH * WPSTRIDE;              // 16n
  float* agg1 = h1 + (size_t)n * NH;                 // 16n
  float* h2   = agg1 + (size_t)n * NH;               // 7n
  float* out  = (float*)d_out;

  int nb = (n + 255) / 256;
  k_deg_init<<<nb, 256, 0, stream>>>(dis, n);
  k_deg_count<<<2048, 256, 0, stream>>>(ei + E, dis, E);
  k_rsqrt<<<nb, 256, 0, stream>>>(dis, n);
  k_w1t<<<(4 * NH * WPSTRIDE + 255) / 256, 256, 0, stream>>>(W1, Wp);

  int nwaves = (n + 15) / 16;                 // 6250
  int g1 = (nwaves + 3) / 4;                  // 4 waves per 256-block
  k_gemm1<<<g1, 256, 0, stream>>>(x, W1, Wp, dis, h1, agg1, n);

  k_scatter1<<<4096, 256, 0, stream>>>(ei, dis, h1, agg1, E);
  k_gemm2<<<nb, 256, 0, stream>>>(agg1, b1, W2, dis, h2, out, n);
  k_scatter2<<<2048, 256, 0, stream>>>(ei, dis, h2, out, E);
  k_final<<<nb, 256, 0, stream>>>(b2, out, n);
}

// Round 2
// 1380.325 us; speedup vs baseline: 2.0562x; 2.0562x over previous
//
#include <hip/hip_runtime.h>
#include <math.h>

#define NF 1433
#define NH 16
#define NC 7
#define WPSTRIDE 1436   // 1433 padded to multiple of 4 (16B-aligned rows)
#define SCAN_BS 256

// ---------------- degree / CSR build ----------------
__global__ void k_zero(int* __restrict__ p, int n) {
  int i = blockIdx.x * blockDim.x + threadIdx.x;
  if (i < n) p[i] = 0;
}

__global__ void k_count(const int* __restrict__ dst, int* __restrict__ cnt, int E) {
  int stride = gridDim.x * blockDim.x;
  for (int e = blockIdx.x * blockDim.x + threadIdx.x; e < E; e += stride)
    atomicAdd(&cnt[dst[e]], 1);
}

__global__ void k_dis(const int* __restrict__ cnt, float* __restrict__ dis, int n) {
  int i = blockIdx.x * blockDim.x + threadIdx.x;
  if (i < n) dis[i] = rsqrtf((float)cnt[i] + 1.0f);  // +1 = self loop
}

// exclusive scan, 3 phases. Phase 1: per-block exclusive scan + block sum.
__global__ void k_scan_block(const int* __restrict__ cnt, int* __restrict__ off,
                             int* __restrict__ bsum, int n) {
  __shared__ int sm[SCAN_BS];
  int t = threadIdx.x, i = blockIdx.x * SCAN_BS + t;
  int v = (i < n) ? cnt[i] : 0;
  sm[t] = v;
  __syncthreads();
  for (int ofs = 1; ofs < SCAN_BS; ofs <<= 1) {
    int u = (t >= ofs) ? sm[t - ofs] : 0;
    __syncthreads();
    sm[t] += u;
    __syncthreads();
  }
  if (i < n) off[i] = sm[t] - v;
  if (t == SCAN_BS - 1) bsum[blockIdx.x] = sm[t];
}

// Phase 2: single block scans the (<=512) block sums; writes off[n] = total.
__global__ void k_scan_bsum(const int* __restrict__ bsum, int* __restrict__ bofs,
                            int nb2, int* __restrict__ off, int n) {
  __shared__ int sm[512];
  int t = threadIdx.x;
  int v = (t < nb2) ? bsum[t] : 0;
  sm[t] = v;
  __syncthreads();
  for (int ofs = 1; ofs < 512; ofs <<= 1) {
    int u = (t >= ofs) ? sm[t - ofs] : 0;
    __syncthreads();
    sm[t] += u;
    __syncthreads();
  }
  if (t < nb2) bofs[t] = sm[t] - v;
  if (t == 511) off[n] = sm[511];
}

// Phase 3: add block offsets; also init the fill pointers.
__global__ void k_scan_add(int* __restrict__ off, const int* __restrict__ bofs,
                           int* __restrict__ ptr, int n) {
  int i = blockIdx.x * SCAN_BS + threadIdx.x;
  if (i < n) {
    int o = off[i] + bofs[blockIdx.x];
    off[i] = o;
    ptr[i] = o;
  }
}

__global__ void k_fill(const int* __restrict__ ei, int* __restrict__ ptr,
                       int* __restrict__ srcs, int E) {
  int stride = gridDim.x * blockDim.x;
  for (int e = blockIdx.x * blockDim.x + threadIdx.x; e < E; e += stride) {
    int d = ei[E + e];
    int slot = atomicAdd(&ptr[d], 1);
    srcs[slot] = ei[e];
  }
}

// ---------------- W1 phase-shifted transpose ----------------
__global__ void k_w1t(const float* __restrict__ W1, float* __restrict__ Wp) {
  int t = blockIdx.x * blockDim.x + threadIdx.x;
  if (t >= 4 * NH * WPSTRIDE) return;
  int u = t % WPSTRIDE;
  int j = (t / WPSTRIDE) % NH;
  int s = t / (WPSTRIDE * NH);
  int k = u + s;
  Wp[t] = (k < NF) ? W1[k * NH + j] : 0.0f;
}

// ---------------- GEMM1: hs1 = (x @ W1) * dis[row] ----------------
__global__ __launch_bounds__(256) void k_gemm1(
    const float* __restrict__ x, const float* __restrict__ W1,
    const float* __restrict__ Wp, const float* __restrict__ dis,
    float* __restrict__ hs1, int n) {
  int wave = (blockIdx.x * blockDim.x + threadIdx.x) >> 6;
  int lane = threadIdx.x & 63;
  int nwaves = (n + 15) >> 4;
  if (wave >= nwaves) return;
  int q = lane >> 4, j = lane & 15;
  int base = wave << 4;

  float acc[4] = {0.f, 0.f, 0.f, 0.f};
  int rows[4];
  const float* xr[4];
#pragma unroll
  for (int r = 0; r < 4; ++r) {
    rows[r] = base + q + 4 * r;
    xr[r] = x + (size_t)rows[r] * NF;
  }

  if (base + 15 < n) {  // n divisible by 16 -> always taken
    int s = (4 - q) & 3;
    const float4* wv = (const float4*)(Wp + (size_t)(s * NH + j) * WPSTRIDE);
    const float4* xv[4];
#pragma unroll
    for (int r = 0; r < 4; ++r) xv[r] = (const float4*)(xr[r] + s);

    for (int k = 0; k < s; ++k) {
      float w = W1[k * NH + j];
#pragma unroll
      for (int r = 0; r < 4; ++r) acc[r] = fmaf(xr[r][k], w, acc[r]);
    }
#pragma unroll 4
    for (int m = 0; m < 357; ++m) {
      float4 w = wv[m];
#pragma unroll
      for (int r = 0; r < 4; ++r) {
        float4 xx = xv[r][m];
        acc[r] = fmaf(xx.x, w.x, acc[r]);
        acc[r] = fmaf(xx.y, w.y, acc[r]);
        acc[r] = fmaf(xx.z, w.z, acc[r]);
        acc[r] = fmaf(xx.w, w.w, acc[r]);
      }
    }
    for (int k = s + 1428; k < NF; ++k) {
      float w = W1[k * NH + j];
#pragma unroll
      for (int r = 0; r < 4; ++r) acc[r] = fmaf(xr[r][k], w, acc[r]);
    }
  } else {
    for (int r = 0; r < 4; ++r) {
      if (rows[r] >= n) continue;
      float a = 0.f;
      for (int k = 0; k < NF; ++k) a = fmaf(xr[r][k], W1[k * NH + j], a);
      acc[r] = a;
    }
  }

#pragma unroll
  for (int r = 0; r < 4; ++r)
    if (rows[r] < n)
      hs1[(size_t)rows[r] * NH + j] = acc[r] * dis[rows[r]];
}

// ---------------- pull layer 1: v1 = relu(dis[d]*(hs1[d] + sum_in hs1[s]) + b1)
__global__ __launch_bounds__(256) void k_pull1(
    const int* __restrict__ off, const int* __restrict__ srcs,
    const float* __restrict__ dis, const float* __restrict__ hs1,
    const float* __restrict__ b1, float* __restrict__ v1, int n) {
  int gid = (blockIdx.x * blockDim.x + threadIdx.x) >> 4;  // 16 lanes / node
  int j = threadIdx.x & 15;
  if (gid >= n) return;
  int d = gid;
  float acc = hs1[(size_t)d * NH + j];  // self loop
  int k = off[d], k1 = off[d + 1];
  for (; k + 1 < k1; k += 2) {
    int s0 = srcs[k], s1 = srcs[k + 1];
    float a0 = hs1[(size_t)s0 * NH + j];
    float a1 = hs1[(size_t)s1 * NH + j];
    acc += a0 + a1;
  }
  if (k < k1) acc += hs1[(size_t)srcs[k] * NH + j];
  v1[(size_t)d * NH + j] = fmaxf(acc * dis[d] + b1[j], 0.f);
}

// ---------------- GEMM2: hs2 = (v1 @ W2) * dis ----------------
__global__ void k_gemm2(const float* __restrict__ v1, const float* __restrict__ W2,
                        const float* __restrict__ dis, float* __restrict__ hs2, int n) {
  int i = blockIdx.x * blockDim.x + threadIdx.x;
  if (i >= n) return;
  float v[NH];
  const float4* a4 = (const float4*)(v1 + (size_t)i * NH);
#pragma unroll
  for (int jj = 0; jj < 4; ++jj) {
    float4 t = a4[jj];
    v[jj * 4 + 0] = t.x; v[jj * 4 + 1] = t.y; v[jj * 4 + 2] = t.z; v[jj * 4 + 3] = t.w;
  }
  float d = dis[i];
#pragma unroll
  for (int c = 0; c < NC; ++c) {
    float s = 0.f;
#pragma unroll
    for (int j = 0; j < NH; ++j) s = fmaf(v[j], W2[j * NC + c], s);
    hs2[(size_t)i * NC + c] = s * d;
  }
}

// ---------------- pull layer 2 + bias + relu + log_softmax ----------------
__global__ __launch_bounds__(256) void k_pull2(
    const int* __restrict__ off, const int* __restrict__ srcs,
    const float* __restrict__ dis, const float* __restrict__ hs2,
    const float* __restrict__ b2, float* __restrict__ out, int n) {
  int gid = (blockIdx.x * blockDim.x + threadIdx.x) >> 3;  // 8 lanes / node
  int j = threadIdx.x & 7;
  if (gid >= n) return;
  int d = gid;
  bool act = (j < NC);
  float acc = act ? hs2[(size_t)d * NC + j] : 0.f;  // self loop
  int k = off[d], k1 = off[d + 1];
  for (; k + 1 < k1; k += 2) {
    int s0 = srcs[k], s1 = srcs[k + 1];
    float a0 = act ? hs2[(size_t)s0 * NC + j] : 0.f;
    float a1 = act ? hs2[(size_t)s1 * NC + j] : 0.f;
    acc += a0 + a1;
  }
  if (k < k1 && act) acc += hs2[(size_t)srcs[k] * NC + j];

  float u = act ? fmaxf(acc * dis[d] + b2[j], 0.f) : -INFINITY;
  float m = u;
#pragma unroll
  for (int w = 1; w < 8; w <<= 1) m = fmaxf(m, __shfl_xor(m, w, 8));
  float e = act ? expf(u - m) : 0.f;
  float ssum = e;
#pragma unroll
  for (int w = 1; w < 8; w <<= 1) ssum += __shfl_xor(ssum, w, 8);
  if (act) out[(size_t)d * NC + j] = u - m - logf(ssum);
}

extern "C" void kernel_launch(void* const* d_in, const int* in_sizes, int n_in,
                              void* d_out, int out_size, void* d_ws, size_t ws_size,
                              hipStream_t stream) {
  const float* x  = (const float*)d_in[0];
  const int*   ei = (const int*)d_in[1];
  const float* W1 = (const float*)d_in[2];
  const float* b1 = (const float*)d_in[3];
  const float* W2 = (const float*)d_in[4];
  const float* b2 = (const float*)d_in[5];
  int n = in_sizes[0] / NF;   // 100000
  int E = in_sizes[1] / 2;    // 3200000

  // workspace layout
  char* w = (char*)d_ws;
  float* dis  = (float*)w;                 w += sizeof(float) * n;
  float* Wp   = (float*)w;                 w += sizeof(float) * 4 * NH * WPSTRIDE;
  float* hs1  = (float*)w;                 w += sizeof(float) * (size_t)n * NH;
  float* v1   = (float*)w;                 w += sizeof(float) * (size_t)n * NH;
  float* hs2  = (float*)w;                 w += sizeof(float) * (size_t)n * NC;
  int* cnt    = (int*)w;                   w += sizeof(int) * n;
  int* off    = (int*)w;                   w += sizeof(int) * (n + 1);
  int* ptr    = (int*)w;                   w += sizeof(int) * n;
  int* srcs   = (int*)w;                   w += sizeof(int) * (size_t)E;
  int* bsum   = (int*)w;                   w += sizeof(int) * 512;
  int* bofs   = (int*)w;                   /* +512 */
  float* out  = (float*)d_out;

  int nb = (n + 255) / 256;
  int nscan = (n + SCAN_BS - 1) / SCAN_BS;   // 391 <= 512

  // CSR build
  k_zero<<<nb, 256, 0, stream>>>(cnt, n);
  k_count<<<2048, 256, 0, stream>>>(ei + E, cnt, E);
  k_dis<<<nb, 256, 0, stream>>>(cnt, dis, n);
  k_scan_block<<<nscan, SCAN_BS, 0, stream>>>(cnt, off, bsum, n);
  k_scan_bsum<<<1, 512, 0, stream>>>(bsum, bofs, nscan, off, n);
  k_scan_add<<<nscan, SCAN_BS, 0, stream>>>(off, bofs, ptr, n);
  k_fill<<<2048, 256, 0, stream>>>(ei, ptr, srcs, E);

  // features
  k_w1t<<<(4 * NH * WPSTRIDE + 255) / 256, 256, 0, stream>>>(W1, Wp);
  int nwaves = (n + 15) / 16;
  k_gemm1<<<(nwaves + 3) / 4, 256, 0, stream>>>(x, W1, Wp, dis, hs1, n);
  k_pull1<<<(n * 16 + 255) / 256, 256, 0, stream>>>(off, srcs, dis, hs1, b1, v1, n);
  k_gemm2<<<nb, 256, 0, stream>>>(v1, W2, dis, hs2, n);
  k_pull2<<<(n * 8 + 255) / 256, 256, 0, stream>>>(off, srcs, dis, hs2, b2, out, n);
}

// Round 3
// 911.652 us; speedup vs baseline: 3.1132x; 1.5141x over previous
//
#include <hip/hip_runtime.h>
#include <math.h>

#define NF 1433
#define NH 16
#define NC 7
#define SCAN_BS 256
#define XS_STRIDE 68   // dwords; 68*4=272 ≡ 0 mod 16 (b128-aligned rows), 2-way bank alias only
#define KC 64
#define NCH 23         // ceil(1433/64)

// ---------------- degree / CSR build ----------------
__global__ void k_zero(int* __restrict__ p, int n) {
  int i = blockIdx.x * blockDim.x + threadIdx.x;
  if (i < n) p[i] = 0;
}

__global__ void k_count(const int* __restrict__ dst, int* __restrict__ cnt, int E) {
  int stride = gridDim.x * blockDim.x;
  for (int e = blockIdx.x * blockDim.x + threadIdx.x; e < E; e += stride)
    atomicAdd(&cnt[dst[e]], 1);
}

__global__ void k_dis(const int* __restrict__ cnt, float* __restrict__ dis, int n) {
  int i = blockIdx.x * blockDim.x + threadIdx.x;
  if (i < n) dis[i] = rsqrtf((float)cnt[i] + 1.0f);  // +1 = self loop
}

// exclusive scan, 3 phases
__global__ void k_scan_block(const int* __restrict__ cnt, int* __restrict__ off,
                             int* __restrict__ bsum, int n) {
  __shared__ int sm[SCAN_BS];
  int t = threadIdx.x, i = blockIdx.x * SCAN_BS + t;
  int v = (i < n) ? cnt[i] : 0;
  sm[t] = v;
  __syncthreads();
  for (int ofs = 1; ofs < SCAN_BS; ofs <<= 1) {
    int u = (t >= ofs) ? sm[t - ofs] : 0;
    __syncthreads();
    sm[t] += u;
    __syncthreads();
  }
  if (i < n) off[i] = sm[t] - v;
  if (t == SCAN_BS - 1) bsum[blockIdx.x] = sm[t];
}

__global__ void k_scan_bsum(const int* __restrict__ bsum, int* __restrict__ bofs,
                            int nb2, int* __restrict__ off, int n) {
  __shared__ int sm[512];
  int t = threadIdx.x;
  int v = (t < nb2) ? bsum[t] : 0;
  sm[t] = v;
  __syncthreads();
  for (int ofs = 1; ofs < 512; ofs <<= 1) {
    int u = (t >= ofs) ? sm[t - ofs] : 0;
    __syncthreads();
    sm[t] += u;
    __syncthreads();
  }
  if (t < nb2) bofs[t] = sm[t] - v;
  if (t == 511) off[n] = sm[511];
}

__global__ void k_scan_add(int* __restrict__ off, const int* __restrict__ bofs,
                           int* __restrict__ ptr, int n) {
  int i = blockIdx.x * SCAN_BS + threadIdx.x;
  if (i < n) {
    int o = off[i] + bofs[blockIdx.x];
    off[i] = o;
    ptr[i] = o;
  }
}

__global__ void k_fill(const int* __restrict__ ei, int* __restrict__ ptr,
                       int* __restrict__ srcs, int E) {
  int stride = gridDim.x * blockDim.x;
  for (int e = blockIdx.x * blockDim.x + threadIdx.x; e < E; e += stride) {
    int d = ei[E + e];
    int slot = atomicAdd(&ptr[d], 1);
    srcs[slot] = ei[e];
  }
}

// ---------------- GEMM1: hs1 = (x @ W1) * dis[row], LDS-tiled ----------------
// block: 64 rows x 16 cols, K chunks of 64. x staged dword-coalesced (row stride
// 1433 is odd -> no aligned float4 on global side); W chunk transposed in LDS.
// Register-prefetch of chunk c+1 issued before compute of chunk c (T14).
__global__ __launch_bounds__(256) void k_gemm1(
    const float* __restrict__ x, const float* __restrict__ W1,
    const float* __restrict__ dis, float* __restrict__ hs1, int n) {
  __shared__ float xs[64 * XS_STRIDE];
  __shared__ float ws[16 * XS_STRIDE];
  int t = threadIdx.x;
  int wave = t >> 6, lane = t & 63;
  int R = blockIdx.x * 64;
  int j = t & 15, rg = t >> 4;
  int kk = t >> 2, jg = t & 3;

  float xr[16];
  float4 wr;
  // prefetch chunk 0
  {
#pragma unroll
    for (int i = 0; i < 16; ++i) {
      int grow = R + (wave << 4) + i;
      int col = lane;
      xr[i] = (grow < n) ? x[(size_t)grow * NF + col] : 0.f;  // col<64<NF always
    }
    wr = *(const float4*)(W1 + (size_t)kk * NH + jg * 4);     // kk<64<NF
  }

  float acc[4] = {0.f, 0.f, 0.f, 0.f};

  for (int c = 0; c < NCH; ++c) {
    __syncthreads();
    // commit staged regs to LDS
#pragma unroll
    for (int i = 0; i < 16; ++i)
      xs[((wave << 4) + i) * XS_STRIDE + lane] = xr[i];
    ws[(jg * 4 + 0) * XS_STRIDE + kk] = wr.x;
    ws[(jg * 4 + 1) * XS_STRIDE + kk] = wr.y;
    ws[(jg * 4 + 2) * XS_STRIDE + kk] = wr.z;
    ws[(jg * 4 + 3) * XS_STRIDE + kk] = wr.w;
    __syncthreads();
    // prefetch next chunk (issued before compute -> latency hidden)
    if (c + 1 < NCH) {
      int K0 = (c + 1) * KC;
#pragma unroll
      for (int i = 0; i < 16; ++i) {
        int grow = R + (wave << 4) + i;
        int col = K0 + lane;
        xr[i] = (grow < n && col < NF) ? x[(size_t)grow * NF + col] : 0.f;
      }
      int k = K0 + kk;
      wr = (k < NF) ? *(const float4*)(W1 + (size_t)k * NH + jg * 4)
                    : make_float4(0.f, 0.f, 0.f, 0.f);
    }
    // compute from LDS
    const float4* wp = (const float4*)(ws + j * XS_STRIDE);
    const float4* x0 = (const float4*)(xs + (rg * 4 + 0) * XS_STRIDE);
    const float4* x1 = (const float4*)(xs + (rg * 4 + 1) * XS_STRIDE);
    const float4* x2 = (const float4*)(xs + (rg * 4 + 2) * XS_STRIDE);
    const float4* x3 = (const float4*)(xs + (rg * 4 + 3) * XS_STRIDE);
#pragma unroll
    for (int k4 = 0; k4 < 16; ++k4) {
      float4 w = wp[k4];
      float4 a;
      a = x0[k4];
      acc[0] = fmaf(a.x, w.x, acc[0]); acc[0] = fmaf(a.y, w.y, acc[0]);
      acc[0] = fmaf(a.z, w.z, acc[0]); acc[0] = fmaf(a.w, w.w, acc[0]);
      a = x1[k4];
      acc[1] = fmaf(a.x, w.x, acc[1]); acc[1] = fmaf(a.y, w.y, acc[1]);
      acc[1] = fmaf(a.z, w.z, acc[1]); acc[1] = fmaf(a.w, w.w, acc[1]);
      a = x2[k4];
      acc[2] = fmaf(a.x, w.x, acc[2]); acc[2] = fmaf(a.y, w.y, acc[2]);
      acc[2] = fmaf(a.z, w.z, acc[2]); acc[2] = fmaf(a.w, w.w, acc[2]);
      a = x3[k4];
      acc[3] = fmaf(a.x, w.x, acc[3]); acc[3] = fmaf(a.y, w.y, acc[3]);
      acc[3] = fmaf(a.z, w.z, acc[3]); acc[3] = fmaf(a.w, w.w, acc[3]);
    }
  }

#pragma unroll
  for (int r = 0; r < 4; ++r) {
    int grow = R + rg * 4 + r;
    if (grow < n) hs1[(size_t)grow * NH + j] = acc[r] * dis[grow];
  }
}

// ---------------- pull layer 1: v1 = relu(dis[d]*(hs1[d] + sum_in hs1[s]) + b1)
__global__ __launch_bounds__(256) void k_pull1(
    const int* __restrict__ off, const int* __restrict__ srcs,
    const float* __restrict__ dis, const float* __restrict__ hs1,
    const float* __restrict__ b1, float* __restrict__ v1, int n) {
  int gid = (blockIdx.x * blockDim.x + threadIdx.x) >> 4;  // 16 lanes / node
  int j = threadIdx.x & 15;
  if (gid >= n) return;
  int d = gid;
  float acc = hs1[(size_t)d * NH + j];  // self loop
  int k = off[d], k1 = off[d + 1];
  for (; k + 1 < k1; k += 2) {
    int s0 = srcs[k], s1 = srcs[k + 1];
    float a0 = hs1[(size_t)s0 * NH + j];
    float a1 = hs1[(size_t)s1 * NH + j];
    acc += a0 + a1;
  }
  if (k < k1) acc += hs1[(size_t)srcs[k] * NH + j];
  v1[(size_t)d * NH + j] = fmaxf(acc * dis[d] + b1[j], 0.f);
}

// ---------------- GEMM2: hs2 = (v1 @ W2) * dis ----------------
__global__ void k_gemm2(const float* __restrict__ v1, const float* __restrict__ W2,
                        const float* __restrict__ dis, float* __restrict__ hs2, int n) {
  int i = blockIdx.x * blockDim.x + threadIdx.x;
  if (i >= n) return;
  float v[NH];
  const float4* a4 = (const float4*)(v1 + (size_t)i * NH);
#pragma unroll
  for (int jj = 0; jj < 4; ++jj) {
    float4 t = a4[jj];
    v[jj * 4 + 0] = t.x; v[jj * 4 + 1] = t.y; v[jj * 4 + 2] = t.z; v[jj * 4 + 3] = t.w;
  }
  float d = dis[i];
#pragma unroll
  for (int c = 0; c < NC; ++c) {
    float s = 0.f;
#pragma unroll
    for (int j = 0; j < NH; ++j) s = fmaf(v[j], W2[j * NC + c], s);
    hs2[(size_t)i * NC + c] = s * d;
  }
}

// ---------------- pull layer 2 + bias + relu + log_softmax ----------------
__global__ __launch_bounds__(256) void k_pull2(
    const int* __restrict__ off, const int* __restrict__ srcs,
    const float* __restrict__ dis, const float* __restrict__ hs2,
    const float* __restrict__ b2, float* __restrict__ out, int n) {
  int gid = (blockIdx.x * blockDim.x + threadIdx.x) >> 3;  // 8 lanes / node
  int j = threadIdx.x & 7;
  if (gid >= n) return;
  int d = gid;
  bool act = (j < NC);
  float acc = act ? hs2[(size_t)d * NC + j] : 0.f;  // self loop
  int k = off[d], k1 = off[d + 1];
  for (; k + 1 < k1; k += 2) {
    int s0 = srcs[k], s1 = srcs[k + 1];
    float a0 = act ? hs2[(size_t)s0 * NC + j] : 0.f;
    float a1 = act ? hs2[(size_t)s1 * NC + j] : 0.f;
    acc += a0 + a1;
  }
  if (k < k1 && act) acc += hs2[(size_t)srcs[k] * NC + j];

  float u = act ? fmaxf(acc * dis[d] + b2[j], 0.f) : -INFINITY;
  float m = u;
#pragma unroll
  for (int w = 1; w < 8; w <<= 1) m = fmaxf(m, __shfl_xor(m, w, 8));
  float e = act ? expf(u - m) : 0.f;
  float ssum = e;
#pragma unroll
  for (int w = 1; w < 8; w <<= 1) ssum += __shfl_xor(ssum, w, 8);
  if (act) out[(size_t)d * NC + j] = u - m - logf(ssum);
}

extern "C" void kernel_launch(void* const* d_in, const int* in_sizes, int n_in,
                              void* d_out, int out_size, void* d_ws, size_t ws_size,
                              hipStream_t stream) {
  const float* x  = (const float*)d_in[0];
  const int*   ei = (const int*)d_in[1];
  const float* W1 = (const float*)d_in[2];
  const float* b1 = (const float*)d_in[3];
  const float* W2 = (const float*)d_in[4];
  const float* b2 = (const float*)d_in[5];
  int n = in_sizes[0] / NF;   // 100000
  int E = in_sizes[1] / 2;    // 3200000

  // workspace layout
  char* w = (char*)d_ws;
  float* dis  = (float*)w;                 w += sizeof(float) * n;
  float* hs1  = (float*)w;                 w += sizeof(float) * (size_t)n * NH;
  float* v1   = (float*)w;                 w += sizeof(float) * (size_t)n * NH;
  float* hs2  = (float*)w;                 w += sizeof(float) * (size_t)n * NC;
  int* cnt    = (int*)w;                   w += sizeof(int) * n;
  int* off    = (int*)w;                   w += sizeof(int) * (n + 1);
  int* ptr    = (int*)w;                   w += sizeof(int) * n;
  int* srcs   = (int*)w;                   w += sizeof(int) * (size_t)E;
  int* bsum   = (int*)w;                   w += sizeof(int) * 512;
  int* bofs   = (int*)w;                   /* +512 */
  float* out  = (float*)d_out;

  int nb = (n + 255) / 256;
  int nscan = (n + SCAN_BS - 1) / SCAN_BS;   // 391 <= 512

  // CSR build
  k_zero<<<nb, 256, 0, stream>>>(cnt, n);
  k_count<<<2048, 256, 0, stream>>>(ei + E, cnt, E);
  k_dis<<<nb, 256, 0, stream>>>(cnt, dis, n);
  k_scan_block<<<nscan, SCAN_BS, 0, stream>>>(cnt, off, bsum, n);
  k_scan_bsum<<<1, 512, 0, stream>>>(bsum, bofs, nscan, off, n);
  k_scan_add<<<nscan, SCAN_BS, 0, stream>>>(off, bofs, ptr, n);
  k_fill<<<2048, 256, 0, stream>>>(ei, ptr, srcs, E);

  // features
  int rb = (n + 63) / 64;                    // 1563
  k_gemm1<<<rb, 256, 0, stream>>>(x, W1, dis, hs1, n);
  k_pull1<<<(n * 16 + 255) / 256, 256, 0, stream>>>(off, srcs, dis, hs1, b1, v1, n);
  k_gemm2<<<nb, 256, 0, stream>>>(v1, W2, dis, hs2, n);
  k_pull2<<<(n * 8 + 255) / 256, 256, 0, stream>>>(off, srcs, dis, hs2, b2, out, n);
}

// Round 4
// 592.890 us; speedup vs baseline: 4.7870x; 1.5376x over previous
//
#include <hip/hip_runtime.h>
#include <math.h>

#define NF 1433
#define NH 16
#define NC 7
#define SCAN_BS 256
#define NCH 45          // ceil(1433/32) K-chunks of 32

typedef __attribute__((ext_vector_type(8))) short bf16x8;
typedef __attribute__((ext_vector_type(4))) float f32x4;

__device__ __forceinline__ short f2bf(float f) {
  unsigned int u = __float_as_uint(f);
  unsigned int r = (u + 0x7FFFu + ((u >> 16) & 1u)) >> 16;  // RNE
  return (short)r;
}

// ---------------- degree / CSR build (4-way sharded atomics) ----------------
__global__ void k_zero(int* __restrict__ p, int n) {
  int i = blockIdx.x * blockDim.x + threadIdx.x;
  if (i < n) p[i] = 0;
}

__global__ void k_count(const int* __restrict__ dst, int* __restrict__ cnt4, int E, int n) {
  int stride = gridDim.x * blockDim.x;
  for (int e = blockIdx.x * blockDim.x + threadIdx.x; e < E; e += stride)
    atomicAdd(&cnt4[(e & 3) * n + dst[e]], 1);
}

__global__ void k_sumdis(const int* __restrict__ cnt4, int* __restrict__ cnt,
                         float* __restrict__ dis, int n) {
  int i = blockIdx.x * blockDim.x + threadIdx.x;
  if (i >= n) return;
  int s = cnt4[i] + cnt4[n + i] + cnt4[2 * n + i] + cnt4[3 * n + i];
  cnt[i] = s;
  dis[i] = rsqrtf((float)s + 1.0f);  // +1 = self loop
}

// exclusive scan, 3 phases
__global__ void k_scan_block(const int* __restrict__ cnt, int* __restrict__ off,
                             int* __restrict__ bsum, int n) {
  __shared__ int sm[SCAN_BS];
  int t = threadIdx.x, i = blockIdx.x * SCAN_BS + t;
  int v = (i < n) ? cnt[i] : 0;
  sm[t] = v;
  __syncthreads();
  for (int ofs = 1; ofs < SCAN_BS; ofs <<= 1) {
    int u = (t >= ofs) ? sm[t - ofs] : 0;
    __syncthreads();
    sm[t] += u;
    __syncthreads();
  }
  if (i < n) off[i] = sm[t] - v;
  if (t == SCAN_BS - 1) bsum[blockIdx.x] = sm[t];
}

__global__ void k_scan_bsum(const int* __restrict__ bsum, int* __restrict__ bofs,
                            int nb2, int* __restrict__ off, int n) {
  __shared__ int sm[512];
  int t = threadIdx.x;
  int v = (t < nb2) ? bsum[t] : 0;
  sm[t] = v;
  __syncthreads();
  for (int ofs = 1; ofs < 512; ofs <<= 1) {
    int u = (t >= ofs) ? sm[t - ofs] : 0;
    __syncthreads();
    sm[t] += u;
    __syncthreads();
  }
  if (t < nb2) bofs[t] = sm[t] - v;
  if (t == 511) off[n] = sm[511];
}

__global__ void k_scan_add(int* __restrict__ off, const int* __restrict__ bofs, int n) {
  int i = blockIdx.x * SCAN_BS + threadIdx.x;
  if (i < n) off[i] += bofs[blockIdx.x];
}

__global__ void k_ptr4(const int* __restrict__ off, const int* __restrict__ cnt4,
                       int* __restrict__ ptr4, int n) {
  int i = blockIdx.x * blockDim.x + threadIdx.x;
  if (i >= n) return;
  int p = off[i];
  ptr4[i] = p;          p += cnt4[i];
  ptr4[n + i] = p;      p += cnt4[n + i];
  ptr4[2 * n + i] = p;  p += cnt4[2 * n + i];
  ptr4[3 * n + i] = p;
}

__global__ void k_fill(const int* __restrict__ ei, int* __restrict__ ptr4,
                       int* __restrict__ srcs, int E, int n) {
  int stride = gridDim.x * blockDim.x;
  for (int e = blockIdx.x * blockDim.x + threadIdx.x; e < E; e += stride) {
    int d = ei[E + e];
    int slot = atomicAdd(&ptr4[(e & 3) * n + d], 1);
    srcs[slot] = ei[e];
  }
}

// ---------------- W1 -> per-chunk bf16 B-fragments ----------------
// Wb[(c*64 + lane)*8 + i] = bf16(W1[k][col]), k = c*32 + (lane>>4)*8 + i, col = lane&15.
// Same k-map as the A-side x loads -> layout-consistent contraction.
__global__ void k_wpack(const float* __restrict__ W1, short* __restrict__ Wb) {
  int t = blockIdx.x * blockDim.x + threadIdx.x;
  if (t >= NCH * 64 * 8) return;
  int i = t & 7, l = (t >> 3) & 63, c = t >> 9;
  int g = l >> 4, col = l & 15;
  int k = c * 32 + g * 8 + i;
  float v = (k < NF) ? W1[(size_t)k * NH + col] : 0.f;
  Wb[t] = f2bf(v);
}

// ---------------- GEMM1 (MFMA bf16, no LDS): hs1 = (x @ W1) * dis[row] -----
// wave owns 64 rows x 16 cols = 4 MFMA row-tiles. A-frags loaded straight from
// global (x used exactly once -> LDS staging is pure overhead), cvt to bf16 in
// regs, W B-frags prepacked. No barriers; 2-wave blocks for dispatch balance.
__global__ __launch_bounds__(128) void k_gemm1(
    const float* __restrict__ x, const short* __restrict__ Wb,
    const float* __restrict__ dis, float* __restrict__ hs1, int n) {
  int l = threadIdx.x & 63;
  int row0 = blockIdx.x * 128 + (threadIdx.x >> 6) * 64;
  int rl = l & 15, g = l >> 4;

  const float* xp[4];
#pragma unroll
  for (int rt = 0; rt < 4; ++rt) {
    int r = row0 + rt * 16 + rl;
    int rc = r < n ? r : n - 1;           // clamp: garbage rows masked at store
    xp[rt] = x + (size_t)rc * NF + g * 8;
  }
  const bf16x8* wp = (const bf16x8*)Wb + l;

  f32x4 acc[4];
#pragma unroll
  for (int rt = 0; rt < 4; ++rt)
#pragma unroll
    for (int j = 0; j < 4; ++j) acc[rt][j] = 0.f;

  float xa[4][8];
  // preload chunk 0 (k = g*8+i < 64 < NF, always in-row)
#pragma unroll
  for (int rt = 0; rt < 4; ++rt)
#pragma unroll
    for (int i = 0; i < 8; ++i) xa[rt][i] = xp[rt][i];

  for (int c = 0; c < NCH; ++c) {
    bf16x8 bfr = wp[(size_t)c * 64];
    bf16x8 af[4];
#pragma unroll
    for (int rt = 0; rt < 4; ++rt)
#pragma unroll
      for (int i = 0; i < 8; ++i) af[rt][i] = f2bf(xa[rt][i]);

    // prefetch next chunk before the MFMAs (latency hides under matrix pipe)
    if (c + 1 < NCH) {
      int base = (c + 1) * 32;
      if (c + 1 == NCH - 1) {  // tail chunk: k = 1408 + g*8 + i, guard k < NF
#pragma unroll
        for (int rt = 0; rt < 4; ++rt)
#pragma unroll
          for (int i = 0; i < 8; ++i)
            xa[rt][i] = (base + g * 8 + i < NF) ? xp[rt][base + i] : 0.f;
      } else {
#pragma unroll
        for (int rt = 0; rt < 4; ++rt)
#pragma unroll
          for (int i = 0; i < 8; ++i) xa[rt][i] = xp[rt][base + i];
      }
    }

#pragma unroll
    for (int rt = 0; rt < 4; ++rt)
      acc[rt] = __builtin_amdgcn_mfma_f32_16x16x32_bf16(af[rt], bfr, acc[rt], 0, 0, 0);
  }

  // D layout (m89-verified): col = lane&15, row_in_tile = (lane>>4)*4 + reg
#pragma unroll
  for (int rt = 0; rt < 4; ++rt) {
#pragma unroll
    for (int r = 0; r < 4; ++r) {
      int row = row0 + rt * 16 + g * 4 + r;
      if (row < n) hs1[(size_t)row * NH + rl] = acc[rt][r] * dis[row];
    }
  }
}

// ---------------- pull layer 1: v1 = relu(dis[d]*(hs1[d] + sum_in hs1[s]) + b1)
__global__ __launch_bounds__(256) void k_pull1(
    const int* __restrict__ off, const int* __restrict__ srcs,
    const float* __restrict__ dis, const float* __restrict__ hs1,
    const float* __restrict__ b1, float* __restrict__ v1, int n) {
  int gid = (blockIdx.x * blockDim.x + threadIdx.x) >> 4;  // 16 lanes / node
  int j = threadIdx.x & 15;
  if (gid >= n) return;
  int d = gid;
  float acc = hs1[(size_t)d * NH + j];  // self loop
  int k = off[d], k1 = off[d + 1];
  for (; k + 1 < k1; k += 2) {
    int s0 = srcs[k], s1 = srcs[k + 1];
    float a0 = hs1[(size_t)s0 * NH + j];
    float a1 = hs1[(size_t)s1 * NH + j];
    acc += a0 + a1;
  }
  if (k < k1) acc += hs1[(size_t)srcs[k] * NH + j];
  v1[(size_t)d * NH + j] = fmaxf(acc * dis[d] + b1[j], 0.f);
}

// ---------------- GEMM2: hs2 = (v1 @ W2) * dis ----------------
__global__ void k_gemm2(const float* __restrict__ v1, const float* __restrict__ W2,
                        const float* __restrict__ dis, float* __restrict__ hs2, int n) {
  int i = blockIdx.x * blockDim.x + threadIdx.x;
  if (i >= n) return;
  float v[NH];
  const float4* a4 = (const float4*)(v1 + (size_t)i * NH);
#pragma unroll
  for (int jj = 0; jj < 4; ++jj) {
    float4 t = a4[jj];
    v[jj * 4 + 0] = t.x; v[jj * 4 + 1] = t.y; v[jj * 4 + 2] = t.z; v[jj * 4 + 3] = t.w;
  }
  float d = dis[i];
#pragma unroll
  for (int c = 0; c < NC; ++c) {
    float s = 0.f;
#pragma unroll
    for (int j = 0; j < NH; ++j) s = fmaf(v[j], W2[j * NC + c], s);
    hs2[(size_t)i * NC + c] = s * d;
  }
}

// ---------------- pull layer 2 + bias + relu + log_softmax ----------------
__global__ __launch_bounds__(256) void k_pull2(
    const int* __restrict__ off, const int* __restrict__ srcs,
    const float* __restrict__ dis, const float* __restrict__ hs2,
    const float* __restrict__ b2, float* __restrict__ out, int n) {
  int gid = (blockIdx.x * blockDim.x + threadIdx.x) >> 3;  // 8 lanes / node
  int j = threadIdx.x & 7;
  if (gid >= n) return;
  int d = gid;
  bool act = (j < NC);
  float acc = act ? hs2[(size_t)d * NC + j] : 0.f;  // self loop
  int k = off[d], k1 = off[d + 1];
  for (; k + 1 < k1; k += 2) {
    int s0 = srcs[k], s1 = srcs[k + 1];
    float a0 = act ? hs2[(size_t)s0 * NC + j] : 0.f;
    float a1 = act ? hs2[(size_t)s1 * NC + j] : 0.f;
    acc += a0 + a1;
  }
  if (k < k1 && act) acc += hs2[(size_t)srcs[k] * NC + j];

  float u = act ? fmaxf(acc * dis[d] + b2[j], 0.f) : -INFINITY;
  float m = u;
#pragma unroll
  for (int w = 1; w < 8; w <<= 1) m = fmaxf(m, __shfl_xor(m, w, 8));
  float e = act ? expf(u - m) : 0.f;
  float ssum = e;
#pragma unroll
  for (int w = 1; w < 8; w <<= 1) ssum += __shfl_xor(ssum, w, 8);
  if (act) out[(size_t)d * NC + j] = u - m - logf(ssum);
}

extern "C" void kernel_launch(void* const* d_in, const int* in_sizes, int n_in,
                              void* d_out, int out_size, void* d_ws, size_t ws_size,
                              hipStream_t stream) {
  const float* x  = (const float*)d_in[0];
  const int*   ei = (const int*)d_in[1];
  const float* W1 = (const float*)d_in[2];
  const float* b1 = (const float*)d_in[3];
  const float* W2 = (const float*)d_in[4];
  const float* b2 = (const float*)d_in[5];
  int n = in_sizes[0] / NF;   // 100000
  int E = in_sizes[1] / 2;    // 3200000

  // workspace layout
  char* w = (char*)d_ws;
  float* dis  = (float*)w;                 w += sizeof(float) * n;
  short* Wb   = (short*)w;                 w += sizeof(short) * NCH * 64 * 8;
  float* hs1  = (float*)w;                 w += sizeof(float) * (size_t)n * NH;
  float* v1   = (float*)w;                 w += sizeof(float) * (size_t)n * NH;
  float* hs2  = (float*)w;                 w += sizeof(float) * (size_t)n * NC;
  int* cnt    = (int*)w;                   w += sizeof(int) * n;
  int* cnt4   = (int*)w;                   w += sizeof(int) * 4 * (size_t)n;
  int* off    = (int*)w;                   w += sizeof(int) * (n + 1);
  int* ptr4   = (int*)w;                   w += sizeof(int) * 4 * (size_t)n;
  int* srcs   = (int*)w;                   w += sizeof(int) * (size_t)E;
  int* bsum   = (int*)w;                   w += sizeof(int) * 512;
  int* bofs   = (int*)w;                   /* +512 */
  float* out  = (float*)d_out;

  int nb = (n + 255) / 256;
  int nscan = (n + SCAN_BS - 1) / SCAN_BS;   // 391 <= 512

  // CSR build (sharded atomics: shard = e&3, distinct cache lines per shard)
  k_zero<<<(4 * n + 255) / 256, 256, 0, stream>>>(cnt4, 4 * n);
  k_count<<<4096, 256, 0, stream>>>(ei + E, cnt4, E, n);
  k_sumdis<<<nb, 256, 0, stream>>>(cnt4, cnt, dis, n);
  k_scan_block<<<nscan, SCAN_BS, 0, stream>>>(cnt, off, bsum, n);
  k_scan_bsum<<<1, 512, 0, stream>>>(bsum, bofs, nscan, off, n);
  k_scan_add<<<nscan, SCAN_BS, 0, stream>>>(off, bofs, n);
  k_ptr4<<<nb, 256, 0, stream>>>(off, cnt4, ptr4, n);
  k_fill<<<4096, 256, 0, stream>>>(ei, ptr4, srcs, E, n);

  // features
  k_wpack<<<(NCH * 64 * 8 + 255) / 256, 256, 0, stream>>>(W1, Wb);
  k_gemm1<<<(n + 127) / 128, 128, 0, stream>>>(x, Wb, dis, hs1, n);
  k_pull1<<<(n * 16 + 255) / 256, 256, 0, stream>>>(off, srcs, dis, hs1, b1, v1, n);
  k_gemm2<<<nb, 256, 0, stream>>>(v1, W2, dis, hs2, n);
  k_pull2<<<(n * 8 + 255) / 256, 256, 0, stream>>>(off, srcs, dis, hs2, b2, out, n);
}